// Round 5
// baseline (142.182 us; speedup 1.0000x reference)
//
#include <hip/hip_runtime.h>
#include <hip/hip_bf16.h>
#include <stdint.h>
#include <stddef.h>

#define BATCH 4096
#define INF   1024
#define OUTF  1024
#define KDIM  8192            // 1024 in-features * 8 spline bases
#define KS    4               // split-K factor
#define KSL   (KDIM / KS)     // 2048 per slice
#define NT    (KSL / 64)      // 32 K-tiles of BK=64 per block

typedef __attribute__((ext_vector_type(8))) short  short8;
typedef __attribute__((ext_vector_type(4))) float  f32x4;

__device__ constexpr float knot(int j) { return (float)(j - 3) * 0.4f - 1.0f; }

// ---------------------------------------------------------------------------
// Kernel 1: B-spline bases. One thread per (b,i); writes 8 bf16 (16 B).
// ---------------------------------------------------------------------------
__global__ __launch_bounds__(256) void kan_bases(const float* __restrict__ x,
                                                 short8* __restrict__ A) {
    size_t idx = (size_t)blockIdx.x * 256 + threadIdx.x;
    float xv = x[idx];

    float b[11];
#pragma unroll
    for (int j = 0; j < 11; ++j)
        b[j] = (xv >= knot(j) && xv < knot(j + 1)) ? 1.0f : 0.0f;

#pragma unroll
    for (int k = 1; k <= 3; ++k) {
#pragma unroll
        for (int j = 0; j + k < 11; ++j) {
            float left  = (xv - knot(j))         * (1.0f / (knot(j + k)     - knot(j)));
            float right = (knot(j + k + 1) - xv) * (1.0f / (knot(j + k + 1) - knot(j + 1)));
            b[j] = left * b[j] + right * b[j + 1];
        }
    }

    union { short8 v; unsigned short u[8]; } pk;
#pragma unroll
    for (int g = 0; g < 8; ++g) {
        __hip_bfloat16 h = __float2bfloat16(b[g]);
        pk.u[g] = *reinterpret_cast<unsigned short*>(&h);
    }
    A[idx] = pk.v;
}

// ---------------------------------------------------------------------------
// Kernel 2: weight fp32 -> bf16 (B^T row-major over k = i*8+g already).
// ---------------------------------------------------------------------------
__global__ __launch_bounds__(256) void kan_wconv(const f32x4* __restrict__ w,
                                                 short8* __restrict__ Wb) {
    size_t idx = (size_t)blockIdx.x * 256 + threadIdx.x;
    f32x4 a = w[idx * 2];
    f32x4 c = w[idx * 2 + 1];
    float t[8] = {a[0], a[1], a[2], a[3], c[0], c[1], c[2], c[3]};
    union { short8 v; unsigned short u[8]; } pk;
#pragma unroll
    for (int g = 0; g < 8; ++g) {
        __hip_bfloat16 h = __float2bfloat16(t[g]);
        pk.u[g] = *reinterpret_cast<unsigned short*>(&h);
    }
    Wb[idx] = pk.v;
}

// ---------------------------------------------------------------------------
// Kernel 3: bf16 GEMM, m201-style 8-phase schedule.
// 256x256 tile, BK=64, split-K=4. 512 threads = 8 waves (2M x 4N), per-wave
// 128x64 (acc[8][4]). Fixed-parity double buffer (128 KiB). Per iter = 2
// K-tiles, 8 phases; each phase: {ds_read subtile | stage 1 half-tile |
// barrier | lgkmcnt(0) | setprio(1) 16xMFMA setprio(0) | barrier}.
// vmcnt(4) only at phases 4 and 8. XOR swizzle (both-sides) as r4.
// ---------------------------------------------------------------------------
__device__ __forceinline__ void gload16(const void* g, void* l) {
    __builtin_amdgcn_global_load_lds((const __attribute__((address_space(1))) void*)g,
                                     (__attribute__((address_space(3))) void*)l,
                                     16, 0, 0);
}

#define MFMA(a, b, c) __builtin_amdgcn_mfma_f32_16x16x32_bf16((a), (b), (c), 0, 0, 0)

__global__ __launch_bounds__(512, 2) void kan_gemm(const __hip_bfloat16* __restrict__ A,
                                                   const __hip_bfloat16* __restrict__ Bt,
                                                   float* __restrict__ C) {
    __shared__ __hip_bfloat16 sA[2][256 * 64];   // 64 KiB (even/odd K-tile)
    __shared__ __hip_bfloat16 sB[2][256 * 64];   // 64 KiB

    const int tid  = threadIdx.x;
    const int orig = blockIdx.x;
    const int sb   = (orig & 7) * 32 + (orig >> 3);   // XCD chunk swizzle (256%8==0)
    const int bm   = sb >> 4;            // 0..15  (16 consecutive share A-panel)
    const int bn   = (sb >> 2) & 3;      // 0..3
    const int ks   = sb & 3;             // 0..3
    const int m0   = bm << 8;
    const int n0   = bn << 8;
    const int k0   = ks * KSL;

    // staging: thread t -> LDS row (t>>3)+r*64, 16B slot (t&7) (linear dest).
    // source col pre-swizzled: LDS[row][slot] = G[row][slot ^ (row&7)].
    const int srow = tid >> 3;                                // 0..63
    const int scol = (((tid & 7) ^ (srow & 7)) << 3);         // elems
    const __hip_bfloat16* gA = A  + (size_t)(m0 + srow) * KDIM + k0 + scol;
    const __hip_bfloat16* gB = Bt + (size_t)(n0 + srow) * KDIM + k0 + scol;
    const int ldst = tid * 8;                                 // + r*4096 elems

#define GLA(buf, kt, r) gload16(gA + (size_t)(kt) * 64 + (size_t)((r) * 64) * KDIM, \
                                &sA[buf][(r) * 4096 + ldst])
#define GLB(buf, kt, r) gload16(gB + (size_t)(kt) * 64 + (size_t)((r) * 64) * KDIM, \
                                &sB[buf][(r) * 4096 + ldst])

    // compute: wave w -> rows [wr*128,+128), cols [wc*64,+64) of the 256x256 tile
    const int w    = tid >> 6;
    const int lane = tid & 63;
    const int wr   = (w >> 2) & 1;       // 0..1
    const int wc   = w & 3;              // 0..3
    const int lr   = lane & 15;
    const int lk   = lane >> 4;          // 0..3
    const int kx0  = (lk ^ (lr & 7)) << 3;   // swizzled elem col (kk=1 -> ^32)
    const int ar0  = (wr << 7) + lr;     // + half*64 + fi*16
    const int br0  = (wc << 6) + lr;     // + fj*16

    f32x4 acc[8][4];
#pragma unroll
    for (int i = 0; i < 8; ++i)
#pragma unroll
        for (int j = 0; j < 4; ++j)
            acc[i][j] = (f32x4){0.0f, 0.0f, 0.0f, 0.0f};

    // --- prologue: tile 0 -> buf0 (8 loads); B(1) -> buf1 (4 loads) ---
    GLA(0, 0, 0); GLA(0, 0, 1); GLA(0, 0, 2); GLA(0, 0, 3);
    GLB(0, 0, 0); GLB(0, 0, 1); GLB(0, 0, 2); GLB(0, 0, 3);
    GLB(1, 1, 0); GLB(1, 1, 1); GLB(1, 1, 2); GLB(1, 1, 3);
    asm volatile("s_waitcnt vmcnt(4)" ::: "memory");   // tile 0 landed; B(1) in flight
    __builtin_amdgcn_s_barrier();

    short8 af[4][2], blo[2][2], bhi[2][2];

#define READ_A(tp, half)                                                           \
        _Pragma("unroll")                                                          \
        for (int fi = 0; fi < 4; ++fi) {                                           \
            af[fi][0] = *reinterpret_cast<const short8*>((tp) + (ar0 + (half)*64 + fi*16)*64 + kx0);        \
            af[fi][1] = *reinterpret_cast<const short8*>((tp) + (ar0 + (half)*64 + fi*16)*64 + (kx0^32));   \
        }
#define READ_B(tp, dst, half)                                                      \
        _Pragma("unroll")                                                          \
        for (int fj = 0; fj < 2; ++fj) {                                           \
            dst[fj][0] = *reinterpret_cast<const short8*>((tp) + (br0 + (half)*32 + fj*16)*64 + kx0);       \
            dst[fj][1] = *reinterpret_cast<const short8*>((tp) + (br0 + (half)*32 + fj*16)*64 + (kx0^32));  \
        }
#define CLUSTER(fibase, fjbase, bsrc)                                              \
        asm volatile("s_waitcnt lgkmcnt(0)" ::: "memory");                         \
        __builtin_amdgcn_s_setprio(1);                                             \
        _Pragma("unroll")                                                          \
        for (int kk = 0; kk < 2; ++kk)                                             \
            _Pragma("unroll")                                                      \
            for (int fi = 0; fi < 4; ++fi)                                         \
                _Pragma("unroll")                                                  \
                for (int fj = 0; fj < 2; ++fj)                                     \
                    acc[(fibase)+fi][(fjbase)+fj] =                                \
                        MFMA(af[fi][kk], bsrc[fj][kk], acc[(fibase)+fi][(fjbase)+fj]); \
        __builtin_amdgcn_s_setprio(0);                                             \
        __builtin_amdgcn_s_barrier();

#pragma unroll 1
    for (int t = 0; t < NT; t += 2) {
        const __hip_bfloat16* tA0 = &sA[0][0];
        const __hip_bfloat16* tB0 = &sB[0][0];
        const __hip_bfloat16* tA1 = &sA[1][0];
        const __hip_bfloat16* tB1 = &sB[1][0];
        const bool g = (t + 2) < NT;

        // ---- tile t (buf0) ----
        // ph1: A-lo frags + B-lo frags | stage A-lo(t+1)->buf1 | MFMA (fi0-3, fj0-1)
        READ_A(tA0, 0); READ_B(tB0, blo, 0);
        GLA(1, t + 1, 0); GLA(1, t + 1, 1);
        __builtin_amdgcn_s_barrier();
        CLUSTER(0, 0, blo);

        // ph2: B-hi frags | stage A-hi(t+1)->buf1 | MFMA (fi0-3, fj2-3)
        READ_B(tB0, bhi, 1);
        GLA(1, t + 1, 2); GLA(1, t + 1, 3);
        __builtin_amdgcn_s_barrier();
        CLUSTER(0, 2, bhi);

        // ph3: A-hi frags | stage B-lo(t+2)->buf0 | MFMA (fi4-7, fj0-1)
        READ_A(tA0, 1);
        if (g) { GLB(0, t + 2, 0); GLB(0, t + 2, 1); }
        __builtin_amdgcn_s_barrier();
        CLUSTER(4, 0, blo);

        // ph4: stage B-hi(t+2)->buf0 | MFMA (fi4-7, fj2-3) | vmcnt: tile t+1 landed
        if (g) { GLB(0, t + 2, 2); GLB(0, t + 2, 3); }
        __builtin_amdgcn_s_barrier();
        asm volatile("s_waitcnt lgkmcnt(0)" ::: "memory");
        __builtin_amdgcn_s_setprio(1);
#pragma unroll
        for (int kk = 0; kk < 2; ++kk)
#pragma unroll
            for (int fi = 0; fi < 4; ++fi)
#pragma unroll
                for (int fj = 0; fj < 2; ++fj)
                    acc[4 + fi][2 + fj] = MFMA(af[fi][kk], bhi[fj][kk], acc[4 + fi][2 + fj]);
        __builtin_amdgcn_s_setprio(0);
        if (g) asm volatile("s_waitcnt vmcnt(4)" ::: "memory");
        else   asm volatile("s_waitcnt vmcnt(0)" ::: "memory");
        __builtin_amdgcn_s_barrier();

        // ---- tile t+1 (buf1) ----
        // ph5: A-lo + B-lo frags | stage A-lo(t+2)->buf0 | MFMA (fi0-3, fj0-1)
        READ_A(tA1, 0); READ_B(tB1, blo, 0);
        if (g) { GLA(0, t + 2, 0); GLA(0, t + 2, 1); }
        __builtin_amdgcn_s_barrier();
        CLUSTER(0, 0, blo);

        // ph6: B-hi frags | stage A-hi(t+2)->buf0 | MFMA (fi0-3, fj2-3)
        READ_B(tB1, bhi, 1);
        if (g) { GLA(0, t + 2, 2); GLA(0, t + 2, 3); }
        __builtin_amdgcn_s_barrier();
        CLUSTER(0, 2, bhi);

        // ph7: A-hi frags | stage B-lo(t+3)->buf1 | MFMA (fi4-7, fj0-1)
        READ_A(tA1, 1);
        if (g) { GLB(1, t + 3, 0); GLB(1, t + 3, 1); }
        __builtin_amdgcn_s_barrier();
        CLUSTER(4, 0, blo);

        // ph8: stage B-hi(t+3)->buf1 | MFMA (fi4-7, fj2-3) | vmcnt: tile t+2 landed
        if (g) { GLB(1, t + 3, 2); GLB(1, t + 3, 3); }
        __builtin_amdgcn_s_barrier();
        asm volatile("s_waitcnt lgkmcnt(0)" ::: "memory");
        __builtin_amdgcn_s_setprio(1);
#pragma unroll
        for (int kk = 0; kk < 2; ++kk)
#pragma unroll
            for (int fi = 0; fi < 4; ++fi)
#pragma unroll
                for (int fj = 0; fj < 2; ++fj)
                    acc[4 + fi][2 + fj] = MFMA(af[fi][kk], bhi[fj][kk], acc[4 + fi][2 + fj]);
        __builtin_amdgcn_s_setprio(0);
        if (g) asm volatile("s_waitcnt vmcnt(4)" ::: "memory");
        else   asm volatile("s_waitcnt vmcnt(0)" ::: "memory");
        __builtin_amdgcn_s_barrier();
    }
#undef GLA
#undef GLB
#undef READ_A
#undef READ_B
#undef CLUSTER

    // --- epilogue: C/D layout col = lane&15, row = (lane>>4)*4 + reg; split-K atomics ---
#pragma unroll
    for (int fi = 0; fi < 8; ++fi) {
#pragma unroll
        for (int fj = 0; fj < 4; ++fj) {
            float* cp = C + (size_t)(m0 + (wr << 7) + fi * 16 + lk * 4) * OUTF
                          + (n0 + (wc << 6) + fj * 16 + lr);
#pragma unroll
            for (int r = 0; r < 4; ++r)
                atomicAdd(cp + (size_t)r * OUTF, acc[fi][fj][r]);
        }
    }
}

// ---------------------------------------------------------------------------
extern "C" void kernel_launch(void* const* d_in, const int* in_sizes, int n_in,
                              void* d_out, int out_size, void* d_ws, size_t ws_size,
                              hipStream_t stream) {
    const float* x = (const float*)d_in[0];       // (4096, 1024) fp32
    const float* w = (const float*)d_in[1];       // (1024, 1024, 8) fp32
    float* out = (float*)d_out;                   // (4096, 1024) fp32

    __hip_bfloat16* Abf = (__hip_bfloat16*)d_ws;                                     // 64 MiB
    __hip_bfloat16* Wbf = (__hip_bfloat16*)((char*)d_ws + (size_t)BATCH * KDIM * 2); // +16 MiB

    kan_bases<<<(BATCH * INF) / 256, 256, 0, stream>>>(x, (short8*)Abf);
    kan_wconv<<<(OUTF * KDIM / 8) / 256, 256, 0, stream>>>((const f32x4*)w, (short8*)Wbf);
    hipMemsetAsync(out, 0, (size_t)BATCH * OUTF * sizeof(float), stream);
    kan_gemm<<<(BATCH / 256) * (OUTF / 256) * KS, 512, 0, stream>>>(Abf, Wbf, out);
}

// Round 6
// 124.508 us; speedup vs baseline: 1.1419x; 1.1419x over previous
//
#include <hip/hip_runtime.h>
#include <hip/hip_bf16.h>
#include <stdint.h>
#include <stddef.h>

#define BATCH 4096
#define INF   1024
#define OUTF  1024
#define KDIM  8192            // 1024 in-features * 8 spline bases
#define KS    2               // split-K factor
#define KSL   (KDIM / KS)     // 4096 per slice
#define NT    (KSL / 64)      // 64 K-tiles of BK=64

typedef __attribute__((ext_vector_type(8))) short  short8;
typedef __attribute__((ext_vector_type(4))) float  f32x4;

__device__ constexpr float knot(int j) { return (float)(j - 3) * 0.4f - 1.0f; }

// ---------------------------------------------------------------------------
// Kernel 1: B-spline bases. One thread per (b,i); writes 8 bf16 (16 B).
// ---------------------------------------------------------------------------
__global__ __launch_bounds__(256) void kan_bases(const float* __restrict__ x,
                                                 short8* __restrict__ A) {
    size_t idx = (size_t)blockIdx.x * 256 + threadIdx.x;
    float xv = x[idx];

    float b[11];
#pragma unroll
    for (int j = 0; j < 11; ++j)
        b[j] = (xv >= knot(j) && xv < knot(j + 1)) ? 1.0f : 0.0f;

#pragma unroll
    for (int k = 1; k <= 3; ++k) {
#pragma unroll
        for (int j = 0; j + k < 11; ++j) {
            float left  = (xv - knot(j))         * (1.0f / (knot(j + k)     - knot(j)));
            float right = (knot(j + k + 1) - xv) * (1.0f / (knot(j + k + 1) - knot(j + 1)));
            b[j] = left * b[j] + right * b[j + 1];
        }
    }

    union { short8 v; unsigned short u[8]; } pk;
#pragma unroll
    for (int g = 0; g < 8; ++g) {
        __hip_bfloat16 h = __float2bfloat16(b[g]);
        pk.u[g] = *reinterpret_cast<unsigned short*>(&h);
    }
    A[idx] = pk.v;
}

// ---------------------------------------------------------------------------
// Kernel 2: weight fp32 -> bf16 (B^T row-major over k = i*8+g already).
// ---------------------------------------------------------------------------
__global__ __launch_bounds__(256) void kan_wconv(const f32x4* __restrict__ w,
                                                 short8* __restrict__ Wb) {
    size_t idx = (size_t)blockIdx.x * 256 + threadIdx.x;
    f32x4 a = w[idx * 2];
    f32x4 c = w[idx * 2 + 1];
    float t[8] = {a[0], a[1], a[2], a[3], c[0], c[1], c[2], c[3]};
    union { short8 v; unsigned short u[8]; } pk;
#pragma unroll
    for (int g = 0; g < 8; ++g) {
        __hip_bfloat16 h = __float2bfloat16(t[g]);
        pk.u[g] = *reinterpret_cast<unsigned short*>(&h);
    }
    Wb[idx] = pk.v;
}

// ---------------------------------------------------------------------------
// Kernel 3: bf16 GEMM, 256x128 tile, BK=64, split-K=2, ring-3 LDS (144 KiB),
// 512 threads = 8 waves (4M x 2N, 64x64 per wave).
// ONE barrier + ONE counted vmcnt(6) per K-tile; tile body is plain C++
// (compiler pipelines ds_read->MFMA with fine-grained lgkmcnt).
// XOR swizzle (both-sides involution) as r4 (0 conflicts measured).
// mode 0: store partials to P (split-K partial buffers, reduced later).
// mode 1: atomicAdd into C (fallback if d_ws too small).
// ---------------------------------------------------------------------------
__device__ __forceinline__ void gload16(const void* g, void* l) {
    __builtin_amdgcn_global_load_lds((const __attribute__((address_space(1))) void*)g,
                                     (__attribute__((address_space(3))) void*)l,
                                     16, 0, 0);
}

#define MFMA(a, b, c) __builtin_amdgcn_mfma_f32_16x16x32_bf16((a), (b), (c), 0, 0, 0)

__global__ __launch_bounds__(512, 2) void kan_gemm(const __hip_bfloat16* __restrict__ A,
                                                   const __hip_bfloat16* __restrict__ Bt,
                                                   float* __restrict__ out,
                                                   int mode) {
    __shared__ __hip_bfloat16 sA[3][256 * 64];   // 96 KiB
    __shared__ __hip_bfloat16 sB[3][128 * 64];   // 48 KiB

    const int tid  = threadIdx.x;
    const int orig = blockIdx.x;
    const int sb   = (orig & 7) * 32 + (orig >> 3);   // XCD chunk swizzle (256%8==0)
    const int bm   = sb >> 4;            // 0..15
    const int bn   = (sb >> 1) & 7;      // 0..7
    const int ks   = sb & 1;             // 0..1
    const int m0   = bm << 8;
    const int n0   = bn << 7;
    const int k0   = ks * KSL;

    // staging: thread t -> LDS row (t>>3)+r*64, 16B slot (t&7) (linear dest).
    // source col pre-swizzled: LDS[row][slot] = G[row][slot ^ (row&7)].
    const int srow = tid >> 3;                                // 0..63
    const int scol = (((tid & 7) ^ (srow & 7)) << 3);         // elems
    const __hip_bfloat16* gA = A  + (size_t)(m0 + srow) * KDIM + k0 + scol;
    const __hip_bfloat16* gB = Bt + (size_t)(n0 + srow) * KDIM + k0 + scol;
    const int ldst = tid * 8;                                 // + r*4096 elems

#define GLA(slot, kt, r) gload16(gA + (size_t)(kt) * 64 + (size_t)((r) * 64) * KDIM, \
                                 &sA[slot][(r) * 4096 + ldst])
#define GLB(slot, kt, r) gload16(gB + (size_t)(kt) * 64 + (size_t)((r) * 64) * KDIM, \
                                 &sB[slot][(r) * 4096 + ldst])

    // compute: wave w -> rows [wr*64,+64), cols [wc*64,+64) of the 256x128 tile
    const int w    = tid >> 6;
    const int lane = tid & 63;
    const int wr   = w >> 1;             // 0..3
    const int wc   = w & 1;              // 0..1
    const int lr   = lane & 15;
    const int lk   = lane >> 4;          // 0..3
    const int kx0  = (lk ^ (lr & 7)) << 3;   // swizzled elem col (kk=1 -> ^32)
    const int ar0  = (wr << 6) + lr;     // + fi*16
    const int br0  = (wc << 6) + lr;     // + fj*16

    f32x4 acc[4][4];
#pragma unroll
    for (int i = 0; i < 4; ++i)
#pragma unroll
        for (int j = 0; j < 4; ++j)
            acc[i][j] = (f32x4){0.0f, 0.0f, 0.0f, 0.0f};

    // --- prologue: stage tiles 0 and 1; wait tile 0 landed ---
    GLA(0, 0, 0); GLA(0, 0, 1); GLA(0, 0, 2); GLA(0, 0, 3); GLB(0, 0, 0); GLB(0, 0, 1);
    GLA(1, 1, 0); GLA(1, 1, 1); GLA(1, 1, 2); GLA(1, 1, 3); GLB(1, 1, 0); GLB(1, 1, 1);
    asm volatile("s_waitcnt vmcnt(6)" ::: "memory");
    __builtin_amdgcn_s_barrier();

    int s = 0;
#pragma unroll 1
    for (int t = 0; t < NT; ++t) {
        const __hip_bfloat16* tA = &sA[s][0];
        const __hip_bfloat16* tB = &sB[s][0];
        const int  s2 = (s >= 1) ? s - 1 : 2;    // (s+2)%3
        const bool pf = (t + 2) < NT;

        // prefetch tile t+2 into slot s2 (readers of s2 finished last iter)
        if (pf) {
            GLA(s2, t + 2, 0); GLA(s2, t + 2, 1); GLA(s2, t + 2, 2); GLA(s2, t + 2, 3);
            GLB(s2, t + 2, 0); GLB(s2, t + 2, 1);
        }
        __builtin_amdgcn_sched_barrier(0);       // keep prefetch issue early

        // tile body: plain reads + MFMAs; compiler pipelines via counted lgkmcnt
        short8 af[4][2], bf[4][2];
#pragma unroll
        for (int fi = 0; fi < 4; ++fi) {
            af[fi][0] = *reinterpret_cast<const short8*>(tA + (ar0 + fi * 16) * 64 + kx0);
            af[fi][1] = *reinterpret_cast<const short8*>(tA + (ar0 + fi * 16) * 64 + (kx0 ^ 32));
        }
#pragma unroll
        for (int fj = 0; fj < 4; ++fj) {
            bf[fj][0] = *reinterpret_cast<const short8*>(tB + (br0 + fj * 16) * 64 + kx0);
            bf[fj][1] = *reinterpret_cast<const short8*>(tB + (br0 + fj * 16) * 64 + (kx0 ^ 32));
        }
#pragma unroll
        for (int kk = 0; kk < 2; ++kk)
#pragma unroll
            for (int fi = 0; fi < 4; ++fi)
#pragma unroll
                for (int fj = 0; fj < 4; ++fj)
                    acc[fi][fj] = MFMA(af[fi][kk], bf[fj][kk], acc[fi][fj]);

        // --- single boundary per K-tile: tile t+1 landed; t+2 stays in flight ---
        if (pf) asm volatile("s_waitcnt vmcnt(6)" ::: "memory");
        else    asm volatile("s_waitcnt vmcnt(0)" ::: "memory");
        __builtin_amdgcn_s_barrier();

        s = (s == 2) ? 0 : s + 1;
    }
#undef GLA
#undef GLB

    // --- epilogue: C/D layout col = lane&15, row = (lane>>4)*4 + reg ---
    if (mode == 0) {
        // partials: plain stores to out = P + ks*(BATCH*OUTF)
        float* P = out + (size_t)ks * BATCH * OUTF;
#pragma unroll
        for (int fi = 0; fi < 4; ++fi) {
#pragma unroll
            for (int fj = 0; fj < 4; ++fj) {
                float* cp = P + (size_t)(m0 + (wr << 6) + fi * 16 + lk * 4) * OUTF
                              + (n0 + (wc << 6) + fj * 16 + lr);
#pragma unroll
                for (int r = 0; r < 4; ++r)
                    cp[(size_t)r * OUTF] = acc[fi][fj][r];
            }
        }
    } else {
        // fallback: atomic accumulate into pre-zeroed C
#pragma unroll
        for (int fi = 0; fi < 4; ++fi) {
#pragma unroll
            for (int fj = 0; fj < 4; ++fj) {
                float* cp = out + (size_t)(m0 + (wr << 6) + fi * 16 + lk * 4) * OUTF
                               + (n0 + (wc << 6) + fj * 16 + lr);
#pragma unroll
                for (int r = 0; r < 4; ++r)
                    atomicAdd(cp + (size_t)r * OUTF, acc[fi][fj][r]);
            }
        }
    }
}

// ---------------------------------------------------------------------------
// Kernel 4: split-K reduce  out = P0 + P1   (16 MiB out, 32 MiB in)
// ---------------------------------------------------------------------------
__global__ __launch_bounds__(256) void kan_reduce(const f32x4* __restrict__ P,
                                                  f32x4* __restrict__ out) {
    size_t i = (size_t)blockIdx.x * 256 + threadIdx.x;   // 1M f32x4
    out[i] = P[i] + P[i + (size_t)BATCH * OUTF / 4];
}

// ---------------------------------------------------------------------------
extern "C" void kernel_launch(void* const* d_in, const int* in_sizes, int n_in,
                              void* d_out, int out_size, void* d_ws, size_t ws_size,
                              hipStream_t stream) {
    const float* x = (const float*)d_in[0];       // (4096, 1024) fp32
    const float* w = (const float*)d_in[1];       // (1024, 1024, 8) fp32
    float* out = (float*)d_out;                   // (4096, 1024) fp32

    const size_t offW = (size_t)BATCH * KDIM * 2;           // Abf: 64 MiB
    const size_t offP = offW + (size_t)OUTF * KDIM * 2;     // Wbf: +16 MiB
    const size_t needP = offP + (size_t)KS * BATCH * OUTF * sizeof(float); // +32 MiB

    __hip_bfloat16* Abf = (__hip_bfloat16*)d_ws;
    __hip_bfloat16* Wbf = (__hip_bfloat16*)((char*)d_ws + offW);
    float*          P   = (float*)((char*)d_ws + offP);
    const bool partials = (ws_size >= needP);

    kan_bases<<<(BATCH * INF) / 256, 256, 0, stream>>>(x, (short8*)Abf);
    kan_wconv<<<(OUTF * KDIM / 8) / 256, 256, 0, stream>>>((const f32x4*)w, (short8*)Wbf);

    const int grid = (BATCH / 256) * (OUTF / 128) * KS;     // 256
    if (partials) {
        kan_gemm<<<grid, 512, 0, stream>>>(Abf, Wbf, P, 0);
        kan_reduce<<<(BATCH * OUTF / 4) / 256, 256, 0, stream>>>((const f32x4*)P, (f32x4*)out);
    } else {
        hipMemsetAsync(out, 0, (size_t)BATCH * OUTF * sizeof(float), stream);
        kan_gemm<<<grid, 512, 0, stream>>>(Abf, Wbf, out, 1);
    }
}